// Round 11
// baseline (643.460 us; speedup 1.0000x reference)
//
#include <hip/hip_runtime.h>
#include <math.h>

#define N_CELLS 1024
#define HID     256
#define N_LOOP  32
#define FLAT    (N_CELLS*HID)   // 262144

typedef float f4 __attribute__((ext_vector_type(4)));

__device__ __forceinline__ float wave_reduce64(float v) {
    #pragma unroll
    for (int m = 32; m; m >>= 1) v += __shfl_xor(v, m);
    return v;
}
__device__ __forceinline__ float dot4(float4 a, float4 b) {
    return a.x*b.x + a.y*b.y + a.z*b.z + a.w*b.w;
}
__device__ __forceinline__ float dot4v(f4 a, float4 b) {
    return a.x*b.x + a.y*b.y + a.z*b.z + a.w*b.w;
}
__device__ __forceinline__ float dot4vv(f4 a, f4 b) {
    return a.x*b.x + a.y*b.y + a.z*b.z + a.w*b.w;
}

// ============ h1 = relu(W1.gi + b1), wave-per-row (256 rows x 288) ============
__global__ void k_gen_h1(const float* __restrict__ x, const float* __restrict__ noise,
                         const float* __restrict__ W1, const float* __restrict__ b1,
                         float* __restrict__ h1) {
    __shared__ __align__(16) float gi[288];
    int t = threadIdx.x, l = t & 63, w = t >> 6;
    gi[t] = x[t];
    if (t < 32) gi[256 + t] = noise[t];
    __syncthreads();
    int j = blockIdx.x * 4 + w;
    const float4* wr = (const float4*)(W1 + j * 288);
    const float4* g4 = (const float4*)gi;
    float acc = dot4(wr[l], g4[l]);
    if (l < 8) acc += dot4(wr[64 + l], g4[64 + l]);
    acc = wave_reduce64(acc);
    if (l == 0) h1[j] = fmaxf(acc + b1[j], 0.f);
}

// ============ h2 = relu(W2.h1 + b2), wave-per-row (512 rows x 256) ============
__global__ void k_gen_h2(const float* __restrict__ h1, const float* __restrict__ W2,
                         const float* __restrict__ b2, float* __restrict__ h2) {
    int t = threadIdx.x, l = t & 63, w = t >> 6;
    int j = blockIdx.x * 4 + w;
    float acc = dot4(((const float4*)(W2 + j * 256))[l], ((const float4*)h1)[l]);
    acc = wave_reduce64(acc);
    if (l == 0) h2[j] = fmaxf(acc + b2[j], 0.f);
}

// ============ gen_states = W3.h2 + b3 — 4 rows/wave, NONTEMPORAL W3 stream ============
__global__ void k_gen_big(const float* __restrict__ W3, const float* __restrict__ b3,
                          const float* __restrict__ h2, float* __restrict__ gs) {
    int t = threadIdx.x, l = t & 63, w = t >> 6;
    int r0 = blockIdx.x * 16 + w * 4;
    const float4* h24 = (const float4*)h2;
    float4 ha = h24[l], hb = h24[64 + l];
    const f4* w0 = (const f4*)(W3 + (size_t)(r0 + 0) * 512);
    const f4* w1 = (const f4*)(W3 + (size_t)(r0 + 1) * 512);
    const f4* w2 = (const f4*)(W3 + (size_t)(r0 + 2) * 512);
    const f4* w3 = (const f4*)(W3 + (size_t)(r0 + 3) * 512);
    f4 A0 = __builtin_nontemporal_load(w0 + l);
    f4 B0 = __builtin_nontemporal_load(w0 + 64 + l);
    f4 A1 = __builtin_nontemporal_load(w1 + l);
    f4 B1 = __builtin_nontemporal_load(w1 + 64 + l);
    f4 A2 = __builtin_nontemporal_load(w2 + l);
    f4 B2 = __builtin_nontemporal_load(w2 + 64 + l);
    f4 A3 = __builtin_nontemporal_load(w3 + l);
    f4 B3 = __builtin_nontemporal_load(w3 + 64 + l);
    float s0 = dot4v(A0, ha) + dot4v(B0, hb);
    float s1 = dot4v(A1, ha) + dot4v(B1, hb);
    float s2 = dot4v(A2, ha) + dot4v(B2, hb);
    float s3 = dot4v(A3, ha) + dot4v(B3, hb);
    s0 = wave_reduce64(s0);
    s1 = wave_reduce64(s1);
    s2 = wave_reduce64(s2);
    s3 = wave_reduce64(s3);
    if (l == 0) {
        float4 bv = *(const float4*)(b3 + r0);
        float4 o; o.x = s0 + bv.x; o.y = s1 + bv.y; o.z = s2 + bv.z; o.w = s3 + bv.w;
        *(float4*)(gs + r0) = o;
    }
}

// ============ per-faction column means — COALESCED float4 row reads ============
// block f (32 blocks, but only 8 used... grid=8): faction f, 256 threads.
// thread (rg = t>>6, c4 = t&63): sums rows rg*32..rg*32+31 at float4-column c4.
__global__ void k_fmean(const float* __restrict__ gs, float* __restrict__ fmean) {
    __shared__ __align__(16) f4 part[4][64];
    int f = blockIdx.x, t = threadIdx.x;
    int rg = t >> 6, c4 = t & 63;
    const f4* base = (const f4*)(gs + (size_t)(f * 128 + rg * 32) * 256) + c4;
    f4 acc = {0.f, 0.f, 0.f, 0.f};
    for (int r = 0; r < 32; ++r) acc += base[r * 64];
    part[rg][c4] = acc;
    __syncthreads();
    if (t < 64) {
        f4 v = (part[0][t] + part[1][t]) + (part[2][t] + part[3][t]);
        v *= (1.f / 128.f);
        *(f4*)(fmean + f * 256 + t * 4) = v;
    }
}

// ============ MEGA (1024 thr): blocks 0..31 = per-sample chain,
//   blocks 32..543 = disc: 2 rows x half-K each (pair p=(b-32)>>1, half=(b-32)&1) ============
__global__ void k_mega(const float* __restrict__ dW1, const float* __restrict__ db1,
                       const float* __restrict__ gs, const float* __restrict__ ch,
                       const float* __restrict__ fmean, const int* __restrict__ step,
                       const float* __restrict__ x,
                       const float* __restrict__ eaW1, const float* __restrict__ eab1,
                       const float* __restrict__ eaW2, const float* __restrict__ eab2,
                       const float* __restrict__ egW1, const float* __restrict__ egb1,
                       const float* __restrict__ egW2, const float* __restrict__ egb2,
                       const float* __restrict__ Wih, const float* __restrict__ bih,
                       const float* __restrict__ Whh, const float* __restrict__ bhh,
                       float* __restrict__ d1rp, float* __restrict__ d1fp,
                       float* __restrict__ outputs, float* __restrict__ tensions,
                       float* __restrict__ out) {
    __shared__ float sA[16], sB[16], sC[16], sD[16];
    __shared__ __align__(16) float fmL[2048];    // 8 KB
    __shared__ __align__(16) float gmL[256];
    __shared__ __align__(16) float xh[512];      // [x | H]
    __shared__ __align__(16) float hag[256];
    __shared__ __align__(16) float outs[256];
    __shared__ float red[256];
    __shared__ float rzA[512];
    __shared__ float inb[256];
    __shared__ float hnb[256];
    __shared__ float tsh;
    int b = blockIdx.x, t = threadIdx.x, l = t & 63, w = t >> 6;
    bool deb = (*step > 5);

    if (b >= 32) {
        // ---- stage fmean + gm into LDS ----
        for (int i = t; i < 2048; i += 1024) fmL[i] = fmean[i];
        __syncthreads();
        if (t < 256) {
            float g = 0.f;
            #pragma unroll
            for (int f = 0; f < 8; ++f) g += fmL[f * 256 + t];
            gmL[t] = g * 0.125f;
        }
        __syncthreads();
        // ---- disc1: rows (2p, 2p+1) over half-K ----
        int idx = b - 32;
        int p = idx >> 1, half = idx & 1;
        int row0 = 2 * p, row1 = 2 * p + 1;
        const f4* wr0 = (const f4*)dW1 + (size_t)row0 * 65536;
        const f4* wr1 = (const f4*)dW1 + (size_t)row1 * 65536;
        const float4* g4 = (const float4*)gs;
        const float4* c4 = (const float4*)ch;
        int kbase = half * 32768;
        float aR0 = 0.f, aF0 = 0.f, aR1 = 0.f, aF1 = 0.f;
        for (int k = 0; k < 32; ++k) {
            int i = kbase + k * 1024 + t;
            f4 ww0 = __builtin_nontemporal_load(wr0 + i);
            f4 ww1 = __builtin_nontemporal_load(wr1 + i);
            int c = i >> 6, d4 = i & 63;
            float4 gv = g4[i], cv = c4[i];
            float4 fmv = *(const float4*)(fmL + ((c >> 7) << 8) + d4 * 4);
            float4 v;
            v.x = 0.85f * gv.x + 0.15f * fmv.x;
            v.y = 0.85f * gv.y + 0.15f * fmv.y;
            v.z = 0.85f * gv.z + 0.15f * fmv.z;
            v.w = 0.85f * gv.w + 0.15f * fmv.w;
            if (deb && ((c & 127) < 32)) {
                float4 gm = *(const float4*)(gmL + d4 * 4);
                v.x = 0.85f * v.x + 0.15f * gm.x;
                v.y = 0.85f * v.y + 0.15f * gm.y;
                v.z = 0.85f * v.z + 0.15f * gm.z;
                v.w = 0.85f * v.w + 0.15f * gm.w;
            }
            float4 nc;
            nc.x = 0.7f * v.x + 0.3f * cv.x;
            nc.y = 0.7f * v.y + 0.3f * cv.y;
            nc.z = 0.7f * v.z + 0.3f * cv.z;
            nc.w = 0.7f * v.w + 0.3f * cv.w;
            aR0 += dot4v(ww0, nc);
            aF0 += dot4v(ww0, gv);
            aR1 += dot4v(ww1, nc);
            aF1 += dot4v(ww1, gv);
        }
        aR0 = wave_reduce64(aR0); aF0 = wave_reduce64(aF0);
        aR1 = wave_reduce64(aR1); aF1 = wave_reduce64(aF1);
        if (l == 0) { sA[w] = aR0; sB[w] = aF0; sC[w] = aR1; sD[w] = aF1; }
        __syncthreads();
        if (t < 16) {
            float a = sA[t], bb = sB[t], c = sC[t], dd = sD[t];
            #pragma unroll
            for (int m = 8; m; m >>= 1) {
                a += __shfl_xor(a, m); bb += __shfl_xor(bb, m);
                c += __shfl_xor(c, m); dd += __shfl_xor(dd, m);
            }
            if (t == 0) {
                d1rp[half * 512 + row0] = a;
                d1fp[half * 512 + row0] = bb;
                d1rp[half * 512 + row1] = c;
                d1fp[half * 512 + row1] = dd;
            }
        }
        return;
    }

    // ---------- chain role: sample i = b (16 waves) ----------
    int i = b;
    if (t < 256) {
        xh[t] = x[t];
        float g = gs[i * 256 + t];
        float gmv = 0.f;
        #pragma unroll
        for (int f = 0; f < 8; ++f) gmv += fmean[f * 256 + t];
        gmv *= 0.125f;
        float v = 0.85f * g + 0.15f * fmean[t];     // cells 0..31 are faction 0
        if (deb) v = 0.85f * v + 0.15f * gmv;
        xh[256 + t] = v;
    }
    __syncthreads();

    // ev layer 1: 16 waves x 16 neurons, wave-per-row 512-dot
    for (int k = 0; k < 16; ++k) {
        int j = w * 16 + k;
        const float* W = (j < 128) ? (eaW1 + (size_t)j * 512) : (egW1 + (size_t)(j - 128) * 512);
        const float4* w4 = (const float4*)W;
        const float4* v4 = (const float4*)xh;
        float acc = dot4(w4[l], v4[l]) + dot4(w4[64 + l], v4[64 + l]);
        acc = wave_reduce64(acc);
        if (l == 0) {
            float bias = (j < 128) ? eab1[j] : egb1[j - 128];
            hag[j] = fmaxf(acc + bias, 0.f);
        }
    }
    __syncthreads();

    // ev layer 2: 16 waves x 16 neurons; lanes 0-31 ea(+), 32-63 eg(-)
    for (int k = 0; k < 16; ++k) {
        int tr = w * 16 + k;
        int sl = l & 31;
        bool lo = (l < 32);
        const float4* wv4 = lo ? (const float4*)(eaW2 + (size_t)tr * 128)
                               : (const float4*)(egW2 + (size_t)tr * 128);
        const float4* h4 = (const float4*)(hag + (lo ? 0 : 128));
        float d_ = dot4(wv4[sl], h4[sl]);
        float acc = lo ? d_ : -d_;
        acc = wave_reduce64(acc);
        if (l == 0) {
            float o = acc + eab2[tr] - egb2[tr];
            outs[tr] = o;
            outputs[i * 256 + tr] = o;
        }
    }
    __syncthreads();

    // tension
    if (t < 256) red[t] = outs[t] * outs[t];
    __syncthreads();
    for (int m = 128; m; m >>= 1) { if (t < m && t + m < 256) red[t] += red[t + m]; __syncthreads(); }
    if (t == 0) { float tn = red[0] * (1.f / 256.f); tensions[i] = tn; tsh = tn; }
    __syncthreads();
    float tn = tsh;

    // GRU matvecs: 16 waves x 48 rows (768 rows)
    {
        float4 ov = ((const float4*)outs)[l];
        float4 Hv = ((const float4*)(xh + 256))[l];
        for (int k = 0; k < 48; ++k) {
            int u = w * 48 + k;
            const float* wr = Wih + (size_t)u * 257;
            float g0 = wr[4*l]*ov.x + wr[4*l+1]*ov.y + wr[4*l+2]*ov.z + wr[4*l+3]*ov.w;
            if (l == 0) g0 += wr[256] * tn;
            float4 wh = ((const float4*)(Whh + (size_t)u * 256))[l];
            float h0 = dot4(wh, Hv);
            if (u < 512) {
                float s = wave_reduce64(g0 + h0);
                if (l == 0) rzA[u] = s + bih[u] + bhh[u];
            } else {
                float sg = wave_reduce64(g0);
                float sh = wave_reduce64(h0);
                if (l == 0) { inb[u - 512] = sg + bih[u]; hnb[u - 512] = sh + bhh[u]; }
            }
        }
    }
    __syncthreads();

    // GRU finish
    if (t < 256) {
        float r = 1.f / (1.f + expf(-rzA[t]));
        float z = 1.f / (1.f + expf(-rzA[256 + t]));
        float nc = tanhf(inb[t] + r * hnb[t]);
        float Hd = xh[256 + t];
        out[259 + i * 256 + t] = (1.f - z) * nc + z * Hd;
    }
}

// ============ epi1: sum half-K partials, disc layer-2 GEMV over 8 blocks ============
__global__ void k_epi1(const float* __restrict__ W2, const float* __restrict__ b2,
                       const float* __restrict__ db1,
                       const float* __restrict__ d1rp, const float* __restrict__ d1fp,
                       float* __restrict__ l2buf) {
    __shared__ __align__(16) float lv[512];
    int b = blockIdx.x, t = threadIdx.x, l = t & 63, w = t >> 6;
    int br = b >> 2, q = b & 3;
    const float* dp = br ? d1fp : d1rp;
    for (int j = t; j < 512; j += 256) {
        float v = dp[j] + dp[512 + j] + db1[j];
        lv[j] = v > 0.f ? v : 0.2f * v;
    }
    __syncthreads();
    const float4* l4 = (const float4*)lv;
    float4 va = l4[l], vb = l4[64 + l];
    for (int k = 0; k < 16; ++k) {
        int tr = q * 64 + w * 16 + k;
        const float4* wr = (const float4*)(W2 + (size_t)tr * 512);
        float acc = dot4(wr[l], va) + dot4(wr[64 + l], vb);
        acc = wave_reduce64(acc);
        if (l == 0) {
            float z = acc + b2[tr];
            l2buf[br * 256 + tr] = z > 0.f ? z : 0.2f * z;
        }
    }
}

// ============ epi2: final dots + sigmoid + mean tension + combine ============
__global__ void k_epi2(const float* __restrict__ W3, const float* __restrict__ b3,
                       const float* __restrict__ l2buf,
                       const float* __restrict__ outputs, const float* __restrict__ tensions,
                       float* __restrict__ out) {
    __shared__ float red[256];
    __shared__ float w[32];
    __shared__ float ts[32];
    int t = threadIdx.x;
    for (int p = 0; p < 2; ++p) {
        red[t] = l2buf[p * 256 + t] * W3[t];
        __syncthreads();
        for (int m = 128; m; m >>= 1) { if (t < m) red[t] += red[t + m]; __syncthreads(); }
        if (t == 0) out[257 + p] = 1.f / (1.f + expf(-(red[0] + b3[0])));
        __syncthreads();
    }
    if (t < 32) ts[t] = tensions[t];
    __syncthreads();
    if (t == 0) {
        float mx = ts[0];
        for (int i = 1; i < 32; ++i) mx = fmaxf(mx, ts[i]);
        float s = 0.f, mean = 0.f;
        for (int i = 0; i < 32; ++i) { float e = expf(ts[i] - mx); w[i] = e; s += e; mean += ts[i]; }
        float inv = 1.f / s;
        for (int i = 0; i < 32; ++i) w[i] *= inv;
        out[256] = mean * (1.f / 32.f);
    }
    __syncthreads();
    float c = 0.f;
    for (int i = 0; i < 32; ++i) c += w[i] * outputs[i * 256 + t];
    out[t] = c;
}

extern "C" void kernel_launch(void* const* d_in, const int* in_sizes, int n_in,
                              void* d_out, int out_size, void* d_ws, size_t ws_size,
                              hipStream_t stream) {
    const float* x     = (const float*)d_in[0];
    const float* noise = (const float*)d_in[1];
    const float* ch    = (const float*)d_in[2];
    const float* gW1   = (const float*)d_in[3];
    const float* gb1   = (const float*)d_in[4];
    const float* gW2   = (const float*)d_in[5];
    const float* gb2   = (const float*)d_in[6];
    const float* gW3   = (const float*)d_in[7];
    const float* gb3   = (const float*)d_in[8];
    const float* dW1   = (const float*)d_in[9];
    const float* db1   = (const float*)d_in[10];
    const float* dW2   = (const float*)d_in[11];
    const float* db2   = (const float*)d_in[12];
    const float* dW3   = (const float*)d_in[13];
    const float* db3   = (const float*)d_in[14];
    const float* eaW1  = (const float*)d_in[15];
    const float* eab1  = (const float*)d_in[16];
    const float* eaW2  = (const float*)d_in[17];
    const float* eab2  = (const float*)d_in[18];
    const float* egW1  = (const float*)d_in[19];
    const float* egb1  = (const float*)d_in[20];
    const float* egW2  = (const float*)d_in[21];
    const float* egb2  = (const float*)d_in[22];
    const float* Wih   = (const float*)d_in[23];
    const float* bih   = (const float*)d_in[24];
    const float* Whh   = (const float*)d_in[25];
    const float* bhh   = (const float*)d_in[26];
    const int*   step  = (const int*)d_in[27];

    float* out = (float*)d_out;
    float* ws  = (float*)d_ws;
    float* h1buf    = ws;                 // 256
    float* h2       = h1buf + 256;        // 512
    float* gs       = h2 + 512;           // 262144
    float* fmean    = gs + 262144;        // 2048
    float* outputs  = fmean + 2048;       // 8192
    float* tensions = outputs + 8192;     // 32
    float* d1rp     = tensions + 32;      // 1024
    float* d1fp     = d1rp + 1024;        // 1024
    float* l2buf    = d1fp + 1024;        // 512

    k_gen_h1<<<64, 256, 0, stream>>>(x, noise, gW1, gb1, h1buf);
    k_gen_h2<<<128, 256, 0, stream>>>(h1buf, gW2, gb2, h2);
    k_gen_big<<<FLAT / 16, 256, 0, stream>>>(gW3, gb3, h2, gs);
    k_fmean<<<8, 256, 0, stream>>>(gs, fmean);
    k_mega<<<544, 1024, 0, stream>>>(dW1, db1, gs, ch, fmean, step, x,
                                     eaW1, eab1, eaW2, eab2,
                                     egW1, egb1, egW2, egb2,
                                     Wih, bih, Whh, bhh,
                                     d1rp, d1fp, outputs, tensions, out);
    k_epi1<<<8, 256, 0, stream>>>(dW2, db2, db1, d1rp, d1fp, l2buf);
    k_epi2<<<1, 256, 0, stream>>>(dW3, db3, l2buf, outputs, tensions, out);
}

// Round 12
// 273.201 us; speedup vs baseline: 2.3553x; 2.3553x over previous
//
#include <hip/hip_runtime.h>
#include <math.h>

#define N_CELLS 1024
#define HID     256
#define IN_DIM  256
#define NOISE_DIM 32
#define OUT_DIM 256
#define N_LOOP  32
#define FLAT    (N_CELLS*HID)   // 262144

typedef float f4 __attribute__((ext_vector_type(4)));

__device__ __forceinline__ float wave_reduce64(float v) {
    #pragma unroll
    for (int m = 32; m; m >>= 1) v += __shfl_xor(v, m);
    return v;
}
__device__ __forceinline__ float dot4(float4 a, float4 b) {
    return a.x*b.x + a.y*b.y + a.z*b.z + a.w*b.w;
}
__device__ __forceinline__ float dot4v(f4 a, float4 b) {
    return a.x*b.x + a.y*b.y + a.z*b.z + a.w*b.w;
}

// ============ h1 = relu(W1.gi + b1), wave-per-row (256 rows x 288) ============
__global__ void k_gen_h1(const float* __restrict__ x, const float* __restrict__ noise,
                         const float* __restrict__ W1, const float* __restrict__ b1,
                         float* __restrict__ h1) {
    __shared__ __align__(16) float gi[288];
    int t = threadIdx.x, l = t & 63, w = t >> 6;
    gi[t] = x[t];
    if (t < 32) gi[256 + t] = noise[t];
    __syncthreads();
    int j = blockIdx.x * 4 + w;
    const float4* wr = (const float4*)(W1 + j * 288);
    const float4* g4 = (const float4*)gi;
    float4 a = wr[l], v = g4[l];
    float acc = dot4(a, v);
    if (l < 8) {
        float4 a2 = wr[64 + l], v2 = g4[64 + l];
        acc += dot4(a2, v2);
    }
    acc = wave_reduce64(acc);
    if (l == 0) h1[j] = fmaxf(acc + b1[j], 0.f);
}

// ============ h2 = relu(W2.h1 + b2), wave-per-row (512 rows x 256) ============
__global__ void k_gen_h2(const float* __restrict__ h1, const float* __restrict__ W2,
                         const float* __restrict__ b2, float* __restrict__ h2) {
    int t = threadIdx.x, l = t & 63, w = t >> 6;
    int j = blockIdx.x * 4 + w;
    float4 a = ((const float4*)(W2 + j * 256))[l];
    float4 v = ((const float4*)h1)[l];
    float acc = dot4(a, v);
    acc = wave_reduce64(acc);
    if (l == 0) h2[j] = fmaxf(acc + b2[j], 0.f);
}

// ============ gen_states = W3.h2 + b3 — 4 rows/wave, NONTEMPORAL W3 stream ============
__global__ void k_gen_big(const float* __restrict__ W3, const float* __restrict__ b3,
                          const float* __restrict__ h2, float* __restrict__ gs) {
    int t = threadIdx.x, l = t & 63, w = t >> 6;
    int r0 = blockIdx.x * 16 + w * 4;            // 16 rows per 256-thr block
    const float4* h24 = (const float4*)h2;
    float4 ha = h24[l], hb = h24[64 + l];
    const f4* w0 = (const f4*)(W3 + (size_t)(r0 + 0) * 512);
    const f4* w1 = (const f4*)(W3 + (size_t)(r0 + 1) * 512);
    const f4* w2 = (const f4*)(W3 + (size_t)(r0 + 2) * 512);
    const f4* w3 = (const f4*)(W3 + (size_t)(r0 + 3) * 512);
    f4 A0 = __builtin_nontemporal_load(w0 + l);
    f4 B0 = __builtin_nontemporal_load(w0 + 64 + l);
    f4 A1 = __builtin_nontemporal_load(w1 + l);
    f4 B1 = __builtin_nontemporal_load(w1 + 64 + l);
    f4 A2 = __builtin_nontemporal_load(w2 + l);
    f4 B2 = __builtin_nontemporal_load(w2 + 64 + l);
    f4 A3 = __builtin_nontemporal_load(w3 + l);
    f4 B3 = __builtin_nontemporal_load(w3 + 64 + l);
    float s0 = dot4v(A0, ha) + dot4v(B0, hb);
    float s1 = dot4v(A1, ha) + dot4v(B1, hb);
    float s2 = dot4v(A2, ha) + dot4v(B2, hb);
    float s3 = dot4v(A3, ha) + dot4v(B3, hb);
    s0 = wave_reduce64(s0);
    s1 = wave_reduce64(s1);
    s2 = wave_reduce64(s2);
    s3 = wave_reduce64(s3);
    if (l == 0) {
        float4 bv = *(const float4*)(b3 + r0);
        float4 o; o.x = s0 + bv.x; o.y = s1 + bv.y; o.z = s2 + bv.z; o.w = s3 + bv.w;
        *(float4*)(gs + r0) = o;
    }
}

// ============ per-faction column means (4-accumulator MLP) ============
__global__ void k_fmean(const float* __restrict__ gs, float* __restrict__ fmean) {
    __shared__ float part[4][64];
    int b = blockIdx.x, t = threadIdx.x;
    int f = b >> 2, q = b & 3;
    int c = q * 64 + (t & 63), rg = t >> 6;
    const float* base = gs + (size_t)(f * 128 + rg * 32) * 256 + c;
    float s0 = 0.f, s1 = 0.f, s2 = 0.f, s3 = 0.f;
    for (int i = 0; i < 32; i += 4) {
        s0 += base[(size_t)(i + 0) * 256];
        s1 += base[(size_t)(i + 1) * 256];
        s2 += base[(size_t)(i + 2) * 256];
        s3 += base[(size_t)(i + 3) * 256];
    }
    part[rg][t & 63] = (s0 + s1) + (s2 + s3);
    __syncthreads();
    if (t < 64) {
        float v = part[0][t] + part[1][t] + part[2][t] + part[3][t];
        fmean[f * 256 + q * 64 + t] = v * (1.f / 128.f);
    }
}

// ============ MEGA (1024 thr): blocks 0..31 = per-sample eval+GRU chain,
//              blocks 32..543 = disc1 rows, NONTEMPORAL dW1 stream ============
__global__ void k_mega(const float* __restrict__ dW1, const float* __restrict__ db1,
                       const float* __restrict__ gs, const float* __restrict__ ch,
                       const float* __restrict__ fmean, const int* __restrict__ step,
                       const float* __restrict__ x,
                       const float* __restrict__ eaW1, const float* __restrict__ eab1,
                       const float* __restrict__ eaW2, const float* __restrict__ eab2,
                       const float* __restrict__ egW1, const float* __restrict__ egb1,
                       const float* __restrict__ egW2, const float* __restrict__ egb2,
                       const float* __restrict__ Wih, const float* __restrict__ bih,
                       const float* __restrict__ Whh, const float* __restrict__ bhh,
                       float* __restrict__ d1r, float* __restrict__ d1f,
                       float* __restrict__ outputs, float* __restrict__ tensions,
                       float* __restrict__ out) {
    __shared__ float sR[16];
    __shared__ float sF[16];
    __shared__ __align__(16) float fmL[2048];    // 8 KB: fmean staged
    __shared__ __align__(16) float gmL[256];     // 1 KB: global mean
    __shared__ __align__(16) float xh[512];      // [x | H]
    __shared__ __align__(16) float hag[256];
    __shared__ __align__(16) float outs[256];
    __shared__ float red[256];
    __shared__ float rzA[512];
    __shared__ float inb[256];
    __shared__ float hnb[256];
    __shared__ float tsh;
    int b = blockIdx.x, t = threadIdx.x, l = t & 63, w = t >> 6;
    bool deb = (*step > 5);

    if (b >= 32) {
        // ---- stage fmean + gm into LDS ----
        for (int i = t; i < 2048; i += 1024) fmL[i] = fmean[i];
        __syncthreads();
        if (t < 256) {
            float g = 0.f;
            #pragma unroll
            for (int f = 0; f < 8; ++f) g += fmL[f * 256 + t];
            gmL[t] = g * 0.125f;
        }
        __syncthreads();
        // ---- disc1: dot dW1[row] against real(ncn, inline) and fake(gs) ----
        int row = b - 32;
        const f4* w4 = (const f4*)(dW1 + (size_t)row * FLAT);
        const float4* g4 = (const float4*)gs;
        const float4* c4 = (const float4*)ch;
        float aR = 0.f, aF = 0.f;
        for (int i = t; i < FLAT / 4; i += 1024) {
            int c = i >> 6, d4 = i & 63;
            f4 ww = __builtin_nontemporal_load(w4 + i);
            float4 gv = g4[i], cv = c4[i];
            float4 fmv = *(const float4*)(fmL + ((c >> 7) << 8) + d4 * 4);
            float4 v;
            v.x = 0.85f * gv.x + 0.15f * fmv.x;
            v.y = 0.85f * gv.y + 0.15f * fmv.y;
            v.z = 0.85f * gv.z + 0.15f * fmv.z;
            v.w = 0.85f * gv.w + 0.15f * fmv.w;
            if (deb && ((c & 127) < 32)) {
                float4 gm = *(const float4*)(gmL + d4 * 4);
                v.x = 0.85f * v.x + 0.15f * gm.x;
                v.y = 0.85f * v.y + 0.15f * gm.y;
                v.z = 0.85f * v.z + 0.15f * gm.z;
                v.w = 0.85f * v.w + 0.15f * gm.w;
            }
            float4 nc;
            nc.x = 0.7f * v.x + 0.3f * cv.x;
            nc.y = 0.7f * v.y + 0.3f * cv.y;
            nc.z = 0.7f * v.z + 0.3f * cv.z;
            nc.w = 0.7f * v.w + 0.3f * cv.w;
            aR += dot4v(ww, nc);
            aF += dot4v(ww, gv);
        }
        aR = wave_reduce64(aR);
        aF = wave_reduce64(aF);
        if (l == 0) { sR[w] = aR; sF[w] = aF; }
        __syncthreads();
        if (t < 16) {
            float r = sR[t], f = sF[t];
            #pragma unroll
            for (int m = 8; m; m >>= 1) { r += __shfl_xor(r, m); f += __shfl_xor(f, m); }
            if (t == 0) { d1r[row] = r + db1[row]; d1f[row] = f + db1[row]; }
        }
        return;
    }

    // ---------- per-sample chain, sample i = b (cells 0..31 are faction 0, debate-set) ----------
    int i = b;
    if (t < 256) {
        xh[t] = x[t];
        float g = gs[i * 256 + t];
        float gmv = 0.f;
        #pragma unroll
        for (int f = 0; f < 8; ++f) gmv += fmean[f * 256 + t];
        gmv *= 0.125f;
        float v = 0.85f * g + 0.15f * fmean[t];     // faction 0
        if (deb) v = 0.85f * v + 0.15f * gmv;
        xh[256 + t] = v;
    }
    __syncthreads();

    // ev layer 1: 16 waves x 16 neurons, wave-per-row 512-dot
    for (int k = 0; k < 16; ++k) {
        int j = w * 16 + k;
        const float* W = (j < 128) ? (eaW1 + (size_t)j * 512) : (egW1 + (size_t)(j - 128) * 512);
        const float4* w4 = (const float4*)W;
        const float4* v4 = (const float4*)xh;
        float acc = dot4(w4[l], v4[l]) + dot4(w4[64 + l], v4[64 + l]);
        acc = wave_reduce64(acc);
        if (l == 0) {
            float bias = (j < 128) ? eab1[j] : egb1[j - 128];
            hag[j] = fmaxf(acc + bias, 0.f);
        }
    }
    __syncthreads();

    // ev layer 2: 16 waves x 16 neurons; lanes 0-31 ea(+), 32-63 eg(-)
    for (int k = 0; k < 16; ++k) {
        int tr = w * 16 + k;
        int sl = l & 31;
        bool lo = (l < 32);
        const float4* wv4 = lo ? (const float4*)(eaW2 + (size_t)tr * 128)
                               : (const float4*)(egW2 + (size_t)tr * 128);
        const float4* h4 = (const float4*)(hag + (lo ? 0 : 128));
        float d_ = dot4(wv4[sl], h4[sl]);
        float acc = lo ? d_ : -d_;
        acc = wave_reduce64(acc);
        if (l == 0) {
            float o = acc + eab2[tr] - egb2[tr];
            outs[tr] = o;
            outputs[i * 256 + tr] = o;
        }
    }
    __syncthreads();

    // tension
    if (t < 256) red[t] = outs[t] * outs[t];
    __syncthreads();
    for (int m = 128; m; m >>= 1) { if (t < m && t + m < 256) red[t] += red[t + m]; __syncthreads(); }
    if (t == 0) { float tn = red[0] * (1.f / 256.f); tensions[i] = tn; tsh = tn; }
    __syncthreads();
    float tn = tsh;

    // GRU matvecs: 16 waves x 48 rows (768 rows)
    {
        float4 ov = ((const float4*)outs)[l];
        float4 Hv = ((const float4*)(xh + 256))[l];
        for (int k = 0; k < 48; ++k) {
            int u = w * 48 + k;
            const float* wr = Wih + (size_t)u * 257;
            float g0 = wr[4*l]*ov.x + wr[4*l+1]*ov.y + wr[4*l+2]*ov.z + wr[4*l+3]*ov.w;
            if (l == 0) g0 += wr[256] * tn;
            float4 wh = ((const float4*)(Whh + (size_t)u * 256))[l];
            float h0 = dot4(wh, Hv);
            if (u < 512) {
                float s = wave_reduce64(g0 + h0);
                if (l == 0) rzA[u] = s + bih[u] + bhh[u];
            } else {
                float sg = wave_reduce64(g0);
                float sh = wave_reduce64(h0);
                if (l == 0) { inb[u - 512] = sg + bih[u]; hnb[u - 512] = sh + bhh[u]; }
            }
        }
    }
    __syncthreads();

    // GRU finish
    if (t < 256) {
        float r = 1.f / (1.f + expf(-rzA[t]));
        float z = 1.f / (1.f + expf(-rzA[256 + t]));
        float nc = tanhf(inb[t] + r * hnb[t]);
        float Hd = xh[256 + t];
        out[259 + i * 256 + t] = (1.f - z) * nc + z * Hd;
    }
}

// ============ epi1: disc layer-2 GEMV spread over 8 blocks (wave-per-row) ============
__global__ void k_epi1(const float* __restrict__ W2, const float* __restrict__ b2,
                       const float* __restrict__ d1r, const float* __restrict__ d1f,
                       float* __restrict__ l2buf) {
    __shared__ __align__(16) float lv[512];
    int b = blockIdx.x, t = threadIdx.x, l = t & 63, w = t >> 6;
    int br = b >> 2, q = b & 3;
    const float* d1 = br ? d1f : d1r;
    for (int j = t; j < 512; j += 256) { float v = d1[j]; lv[j] = v > 0.f ? v : 0.2f * v; }
    __syncthreads();
    const float4* l4 = (const float4*)lv;
    float4 va = l4[l], vb = l4[64 + l];
    for (int k = 0; k < 16; ++k) {
        int tr = q * 64 + w * 16 + k;
        const float4* wr = (const float4*)(W2 + (size_t)tr * 512);
        float acc = dot4(wr[l], va) + dot4(wr[64 + l], vb);
        acc = wave_reduce64(acc);
        if (l == 0) {
            float z = acc + b2[tr];
            l2buf[br * 256 + tr] = z > 0.f ? z : 0.2f * z;
        }
    }
}

// ============ epi2: final disc dots + sigmoid, mean tension, softmax combine ============
__global__ void k_epi2(const float* __restrict__ W3, const float* __restrict__ b3,
                       const float* __restrict__ l2buf,
                       const float* __restrict__ outputs, const float* __restrict__ tensions,
                       float* __restrict__ out) {
    __shared__ float red[256];
    __shared__ float w[32];
    __shared__ float ts[32];
    int t = threadIdx.x;
    for (int p = 0; p < 2; ++p) {
        red[t] = l2buf[p * 256 + t] * W3[t];
        __syncthreads();
        for (int m = 128; m; m >>= 1) { if (t < m) red[t] += red[t + m]; __syncthreads(); }
        if (t == 0) out[257 + p] = 1.f / (1.f + expf(-(red[0] + b3[0])));
        __syncthreads();
    }
    if (t < 32) ts[t] = tensions[t];
    __syncthreads();
    if (t == 0) {
        float mx = ts[0];
        for (int i = 1; i < 32; ++i) mx = fmaxf(mx, ts[i]);
        float s = 0.f, mean = 0.f;
        for (int i = 0; i < 32; ++i) { float e = expf(ts[i] - mx); w[i] = e; s += e; mean += ts[i]; }
        float inv = 1.f / s;
        for (int i = 0; i < 32; ++i) w[i] *= inv;
        out[256] = mean * (1.f / 32.f);
    }
    __syncthreads();
    float c = 0.f;
    for (int i = 0; i < 32; ++i) c += w[i] * outputs[i * 256 + t];
    out[t] = c;
}

extern "C" void kernel_launch(void* const* d_in, const int* in_sizes, int n_in,
                              void* d_out, int out_size, void* d_ws, size_t ws_size,
                              hipStream_t stream) {
    const float* x     = (const float*)d_in[0];
    const float* noise = (const float*)d_in[1];
    const float* ch    = (const float*)d_in[2];
    const float* gW1   = (const float*)d_in[3];
    const float* gb1   = (const float*)d_in[4];
    const float* gW2   = (const float*)d_in[5];
    const float* gb2   = (const float*)d_in[6];
    const float* gW3   = (const float*)d_in[7];
    const float* gb3   = (const float*)d_in[8];
    const float* dW1   = (const float*)d_in[9];
    const float* db1   = (const float*)d_in[10];
    const float* dW2   = (const float*)d_in[11];
    const float* db2   = (const float*)d_in[12];
    const float* dW3   = (const float*)d_in[13];
    const float* db3   = (const float*)d_in[14];
    const float* eaW1  = (const float*)d_in[15];
    const float* eab1  = (const float*)d_in[16];
    const float* eaW2  = (const float*)d_in[17];
    const float* eab2  = (const float*)d_in[18];
    const float* egW1  = (const float*)d_in[19];
    const float* egb1  = (const float*)d_in[20];
    const float* egW2  = (const float*)d_in[21];
    const float* egb2  = (const float*)d_in[22];
    const float* Wih   = (const float*)d_in[23];
    const float* bih   = (const float*)d_in[24];
    const float* Whh   = (const float*)d_in[25];
    const float* bhh   = (const float*)d_in[26];
    const int*   step  = (const int*)d_in[27];

    float* out = (float*)d_out;
    float* ws  = (float*)d_ws;
    float* h1buf    = ws;                 // 256
    float* h2       = h1buf + 256;        // 512
    float* gs       = h2 + 512;           // 262144
    float* fmean    = gs + 262144;        // 2048
    float* outputs  = fmean + 2048;       // 8192
    float* tensions = outputs + 8192;     // 32
    float* d1r      = tensions + 32;      // 512
    float* d1f      = d1r + 512;          // 512
    float* l2buf    = d1f + 512;          // 512

    k_gen_h1<<<64, 256, 0, stream>>>(x, noise, gW1, gb1, h1buf);
    k_gen_h2<<<128, 256, 0, stream>>>(h1buf, gW2, gb2, h2);
    k_gen_big<<<FLAT / 16, 256, 0, stream>>>(gW3, gb3, h2, gs);
    k_fmean<<<32, 256, 0, stream>>>(gs, fmean);
    k_mega<<<544, 1024, 0, stream>>>(dW1, db1, gs, ch, fmean, step, x,
                                     eaW1, eab1, eaW2, eab2,
                                     egW1, egb1, egW2, egb2,
                                     Wih, bih, Whh, bhh,
                                     d1r, d1f, outputs, tensions, out);
    k_epi1<<<8, 256, 0, stream>>>(dW2, db2, d1r, d1f, l2buf);
    k_epi2<<<1, 256, 0, stream>>>(dW3, db3, l2buf, outputs, tensions, out);
}

// Round 13
// 255.392 us; speedup vs baseline: 2.5195x; 1.0697x over previous
//
#include <hip/hip_runtime.h>
#include <math.h>

#define N_CELLS 1024
#define HID     256
#define IN_DIM  256
#define NOISE_DIM 32
#define OUT_DIM 256
#define N_LOOP  32
#define FLAT    (N_CELLS*HID)   // 262144

typedef float f4 __attribute__((ext_vector_type(4)));

__device__ __forceinline__ float wave_reduce64(float v) {
    #pragma unroll
    for (int m = 32; m; m >>= 1) v += __shfl_xor(v, m);
    return v;
}
__device__ __forceinline__ float dot4(float4 a, float4 b) {
    return a.x*b.x + a.y*b.y + a.z*b.z + a.w*b.w;
}
__device__ __forceinline__ float dot4v(f4 a, float4 b) {
    return a.x*b.x + a.y*b.y + a.z*b.z + a.w*b.w;
}

// ============ h1 = relu(W1.gi + b1), wave-per-row (256 rows x 288) ============
__global__ void k_gen_h1(const float* __restrict__ x, const float* __restrict__ noise,
                         const float* __restrict__ W1, const float* __restrict__ b1,
                         float* __restrict__ h1) {
    __shared__ __align__(16) float gi[288];
    int t = threadIdx.x, l = t & 63, w = t >> 6;
    gi[t] = x[t];
    if (t < 32) gi[256 + t] = noise[t];
    __syncthreads();
    int j = blockIdx.x * 4 + w;
    const float4* wr = (const float4*)(W1 + j * 288);
    const float4* g4 = (const float4*)gi;
    float4 a = wr[l], v = g4[l];
    float acc = dot4(a, v);
    if (l < 8) {
        float4 a2 = wr[64 + l], v2 = g4[64 + l];
        acc += dot4(a2, v2);
    }
    acc = wave_reduce64(acc);
    if (l == 0) h1[j] = fmaxf(acc + b1[j], 0.f);
}

// ============ h2 = relu(W2.h1 + b2), wave-per-row (512 rows x 256) ============
__global__ void k_gen_h2(const float* __restrict__ h1, const float* __restrict__ W2,
                         const float* __restrict__ b2, float* __restrict__ h2) {
    int t = threadIdx.x, l = t & 63, w = t >> 6;
    int j = blockIdx.x * 4 + w;
    float4 a = ((const float4*)(W2 + j * 256))[l];
    float4 v = ((const float4*)h1)[l];
    float acc = dot4(a, v);
    acc = wave_reduce64(acc);
    if (l == 0) h2[j] = fmaxf(acc + b2[j], 0.f);
}

// ============ gen_states = W3.h2 + b3 — 4 rows/wave, NONTEMPORAL W3 stream ============
__global__ void k_gen_big(const float* __restrict__ W3, const float* __restrict__ b3,
                          const float* __restrict__ h2, float* __restrict__ gs) {
    int t = threadIdx.x, l = t & 63, w = t >> 6;
    int r0 = blockIdx.x * 16 + w * 4;            // 16 rows per 256-thr block
    const float4* h24 = (const float4*)h2;
    float4 ha = h24[l], hb = h24[64 + l];
    const f4* w0 = (const f4*)(W3 + (size_t)(r0 + 0) * 512);
    const f4* w1 = (const f4*)(W3 + (size_t)(r0 + 1) * 512);
    const f4* w2 = (const f4*)(W3 + (size_t)(r0 + 2) * 512);
    const f4* w3 = (const f4*)(W3 + (size_t)(r0 + 3) * 512);
    f4 A0 = __builtin_nontemporal_load(w0 + l);
    f4 B0 = __builtin_nontemporal_load(w0 + 64 + l);
    f4 A1 = __builtin_nontemporal_load(w1 + l);
    f4 B1 = __builtin_nontemporal_load(w1 + 64 + l);
    f4 A2 = __builtin_nontemporal_load(w2 + l);
    f4 B2 = __builtin_nontemporal_load(w2 + 64 + l);
    f4 A3 = __builtin_nontemporal_load(w3 + l);
    f4 B3 = __builtin_nontemporal_load(w3 + 64 + l);
    float s0 = dot4v(A0, ha) + dot4v(B0, hb);
    float s1 = dot4v(A1, ha) + dot4v(B1, hb);
    float s2 = dot4v(A2, ha) + dot4v(B2, hb);
    float s3 = dot4v(A3, ha) + dot4v(B3, hb);
    s0 = wave_reduce64(s0);
    s1 = wave_reduce64(s1);
    s2 = wave_reduce64(s2);
    s3 = wave_reduce64(s3);
    if (l == 0) {
        float4 bv = *(const float4*)(b3 + r0);
        float4 o; o.x = s0 + bv.x; o.y = s1 + bv.y; o.z = s2 + bv.z; o.w = s3 + bv.w;
        *(float4*)(gs + r0) = o;
    }
}

// ============ per-faction column means (4-accumulator MLP) ============
__global__ void k_fmean(const float* __restrict__ gs, float* __restrict__ fmean) {
    __shared__ float part[4][64];
    int b = blockIdx.x, t = threadIdx.x;
    int f = b >> 2, q = b & 3;
    int c = q * 64 + (t & 63), rg = t >> 6;
    const float* base = gs + (size_t)(f * 128 + rg * 32) * 256 + c;
    float s0 = 0.f, s1 = 0.f, s2 = 0.f, s3 = 0.f;
    for (int i = 0; i < 32; i += 4) {
        s0 += base[(size_t)(i + 0) * 256];
        s1 += base[(size_t)(i + 1) * 256];
        s2 += base[(size_t)(i + 2) * 256];
        s3 += base[(size_t)(i + 3) * 256];
    }
    part[rg][t & 63] = (s0 + s1) + (s2 + s3);
    __syncthreads();
    if (t < 64) {
        float v = part[0][t] + part[1][t] + part[2][t] + part[3][t];
        fmean[f * 256 + q * 64 + t] = v * (1.f / 128.f);
    }
}

// ============ MEGA (1024 thr): blocks 0..31 = per-sample eval+GRU chain,
//   blocks 32..1055 = disc1 half-K pieces (row = idx>>1, half = idx&1), NT dW1 ============
__global__ void k_mega(const float* __restrict__ dW1, const float* __restrict__ db1,
                       const float* __restrict__ gs, const float* __restrict__ ch,
                       const float* __restrict__ fmean, const int* __restrict__ step,
                       const float* __restrict__ x,
                       const float* __restrict__ eaW1, const float* __restrict__ eab1,
                       const float* __restrict__ eaW2, const float* __restrict__ eab2,
                       const float* __restrict__ egW1, const float* __restrict__ egb1,
                       const float* __restrict__ egW2, const float* __restrict__ egb2,
                       const float* __restrict__ Wih, const float* __restrict__ bih,
                       const float* __restrict__ Whh, const float* __restrict__ bhh,
                       float* __restrict__ d1rp, float* __restrict__ d1fp,
                       float* __restrict__ outputs, float* __restrict__ tensions,
                       float* __restrict__ out) {
    __shared__ float sR[16];
    __shared__ float sF[16];
    __shared__ __align__(16) float fmL[2048];    // 8 KB: fmean staged
    __shared__ __align__(16) float gmL[256];     // 1 KB: global mean
    __shared__ __align__(16) float xh[512];      // [x | H]
    __shared__ __align__(16) float hag[256];
    __shared__ __align__(16) float outs[256];
    __shared__ float red[256];
    __shared__ float rzA[512];
    __shared__ float inb[256];
    __shared__ float hnb[256];
    __shared__ float tsh;
    int b = blockIdx.x, t = threadIdx.x, l = t & 63, w = t >> 6;
    bool deb = (*step > 5);

    if (b >= 32) {
        // ---- stage fmean + gm into LDS ----
        for (int i = t; i < 2048; i += 1024) fmL[i] = fmean[i];
        __syncthreads();
        if (t < 256) {
            float g = 0.f;
            #pragma unroll
            for (int f = 0; f < 8; ++f) g += fmL[f * 256 + t];
            gmL[t] = g * 0.125f;
        }
        __syncthreads();
        // ---- disc1 half-K piece: dot dW1[row][half] vs real(ncn inline) and fake(gs) ----
        int idx = b - 32;
        int row = idx >> 1, half = idx & 1;
        const f4* w4 = (const f4*)(dW1 + (size_t)row * FLAT);
        const float4* g4 = (const float4*)gs;
        const float4* c4 = (const float4*)ch;
        int kend = half * 32768 + 32768;
        float aR = 0.f, aF = 0.f;
        for (int i = half * 32768 + t; i < kend; i += 1024) {
            int c = i >> 6, d4 = i & 63;
            f4 ww = __builtin_nontemporal_load(w4 + i);
            float4 gv = g4[i], cv = c4[i];
            float4 fmv = *(const float4*)(fmL + ((c >> 7) << 8) + d4 * 4);
            float4 v;
            v.x = 0.85f * gv.x + 0.15f * fmv.x;
            v.y = 0.85f * gv.y + 0.15f * fmv.y;
            v.z = 0.85f * gv.z + 0.15f * fmv.z;
            v.w = 0.85f * gv.w + 0.15f * fmv.w;
            if (deb && ((c & 127) < 32)) {
                float4 gm = *(const float4*)(gmL + d4 * 4);
                v.x = 0.85f * v.x + 0.15f * gm.x;
                v.y = 0.85f * v.y + 0.15f * gm.y;
                v.z = 0.85f * v.z + 0.15f * gm.z;
                v.w = 0.85f * v.w + 0.15f * gm.w;
            }
            float4 nc;
            nc.x = 0.7f * v.x + 0.3f * cv.x;
            nc.y = 0.7f * v.y + 0.3f * cv.y;
            nc.z = 0.7f * v.z + 0.3f * cv.z;
            nc.w = 0.7f * v.w + 0.3f * cv.w;
            aR += dot4v(ww, nc);
            aF += dot4v(ww, gv);
        }
        aR = wave_reduce64(aR);
        aF = wave_reduce64(aF);
        if (l == 0) { sR[w] = aR; sF[w] = aF; }
        __syncthreads();
        if (t < 16) {
            float r = sR[t], f = sF[t];
            #pragma unroll
            for (int m = 8; m; m >>= 1) { r += __shfl_xor(r, m); f += __shfl_xor(f, m); }
            if (t == 0) { d1rp[half * 512 + row] = r; d1fp[half * 512 + row] = f; }
        }
        return;
    }

    // ---------- per-sample chain, sample i = b (cells 0..31 are faction 0, debate-set) ----------
    int i = b;
    if (t < 256) {
        xh[t] = x[t];
        float g = gs[i * 256 + t];
        float gmv = 0.f;
        #pragma unroll
        for (int f = 0; f < 8; ++f) gmv += fmean[f * 256 + t];
        gmv *= 0.125f;
        float v = 0.85f * g + 0.15f * fmean[t];     // faction 0
        if (deb) v = 0.85f * v + 0.15f * gmv;
        xh[256 + t] = v;
    }
    __syncthreads();

    // ev layer 1: 16 waves x 16 neurons, wave-per-row 512-dot
    for (int k = 0; k < 16; ++k) {
        int j = w * 16 + k;
        const float* W = (j < 128) ? (eaW1 + (size_t)j * 512) : (egW1 + (size_t)(j - 128) * 512);
        const float4* w4 = (const float4*)W;
        const float4* v4 = (const float4*)xh;
        float acc = dot4(w4[l], v4[l]) + dot4(w4[64 + l], v4[64 + l]);
        acc = wave_reduce64(acc);
        if (l == 0) {
            float bias = (j < 128) ? eab1[j] : egb1[j - 128];
            hag[j] = fmaxf(acc + bias, 0.f);
        }
    }
    __syncthreads();

    // ev layer 2: 16 waves x 16 neurons; lanes 0-31 ea(+), 32-63 eg(-)
    for (int k = 0; k < 16; ++k) {
        int tr = w * 16 + k;
        int sl = l & 31;
        bool lo = (l < 32);
        const float4* wv4 = lo ? (const float4*)(eaW2 + (size_t)tr * 128)
                               : (const float4*)(egW2 + (size_t)tr * 128);
        const float4* h4 = (const float4*)(hag + (lo ? 0 : 128));
        float d_ = dot4(wv4[sl], h4[sl]);
        float acc = lo ? d_ : -d_;
        acc = wave_reduce64(acc);
        if (l == 0) {
            float o = acc + eab2[tr] - egb2[tr];
            outs[tr] = o;
            outputs[i * 256 + tr] = o;
        }
    }
    __syncthreads();

    // tension
    if (t < 256) red[t] = outs[t] * outs[t];
    __syncthreads();
    for (int m = 128; m; m >>= 1) { if (t < m && t + m < 256) red[t] += red[t + m]; __syncthreads(); }
    if (t == 0) { float tn = red[0] * (1.f / 256.f); tensions[i] = tn; tsh = tn; }
    __syncthreads();
    float tn = tsh;

    // GRU matvecs: 16 waves x 48 rows (768 rows)
    {
        float4 ov = ((const float4*)outs)[l];
        float4 Hv = ((const float4*)(xh + 256))[l];
        for (int k = 0; k < 48; ++k) {
            int u = w * 48 + k;
            const float* wr = Wih + (size_t)u * 257;
            float g0 = wr[4*l]*ov.x + wr[4*l+1]*ov.y + wr[4*l+2]*ov.z + wr[4*l+3]*ov.w;
            if (l == 0) g0 += wr[256] * tn;
            float4 wh = ((const float4*)(Whh + (size_t)u * 256))[l];
            float h0 = dot4(wh, Hv);
            if (u < 512) {
                float s = wave_reduce64(g0 + h0);
                if (l == 0) rzA[u] = s + bih[u] + bhh[u];
            } else {
                float sg = wave_reduce64(g0);
                float sh = wave_reduce64(h0);
                if (l == 0) { inb[u - 512] = sg + bih[u]; hnb[u - 512] = sh + bhh[u]; }
            }
        }
    }
    __syncthreads();

    // GRU finish
    if (t < 256) {
        float r = 1.f / (1.f + expf(-rzA[t]));
        float z = 1.f / (1.f + expf(-rzA[256 + t]));
        float nc = tanhf(inb[t] + r * hnb[t]);
        float Hd = xh[256 + t];
        out[259 + i * 256 + t] = (1.f - z) * nc + z * Hd;
    }
}

// ============ epi1: sum half-K partials (+bias), disc layer-2 GEMV over 8 blocks ============
__global__ void k_epi1(const float* __restrict__ W2, const float* __restrict__ b2,
                       const float* __restrict__ db1,
                       const float* __restrict__ d1rp, const float* __restrict__ d1fp,
                       float* __restrict__ l2buf) {
    __shared__ __align__(16) float lv[512];
    int b = blockIdx.x, t = threadIdx.x, l = t & 63, w = t >> 6;
    int br = b >> 2, q = b & 3;
    const float* dp = br ? d1fp : d1rp;
    for (int j = t; j < 512; j += 256) {
        float v = dp[j] + dp[512 + j] + db1[j];
        lv[j] = v > 0.f ? v : 0.2f * v;
    }
    __syncthreads();
    const float4* l4 = (const float4*)lv;
    float4 va = l4[l], vb = l4[64 + l];
    for (int k = 0; k < 16; ++k) {
        int tr = q * 64 + w * 16 + k;
        const float4* wr = (const float4*)(W2 + (size_t)tr * 512);
        float acc = dot4(wr[l], va) + dot4(wr[64 + l], vb);
        acc = wave_reduce64(acc);
        if (l == 0) {
            float z = acc + b2[tr];
            l2buf[br * 256 + tr] = z > 0.f ? z : 0.2f * z;
        }
    }
}

// ============ epi2: final disc dots + sigmoid, mean tension, softmax combine ============
__global__ void k_epi2(const float* __restrict__ W3, const float* __restrict__ b3,
                       const float* __restrict__ l2buf,
                       const float* __restrict__ outputs, const float* __restrict__ tensions,
                       float* __restrict__ out) {
    __shared__ float red[256];
    __shared__ float w[32];
    __shared__ float ts[32];
    int t = threadIdx.x;
    for (int p = 0; p < 2; ++p) {
        red[t] = l2buf[p * 256 + t] * W3[t];
        __syncthreads();
        for (int m = 128; m; m >>= 1) { if (t < m) red[t] += red[t + m]; __syncthreads(); }
        if (t == 0) out[257 + p] = 1.f / (1.f + expf(-(red[0] + b3[0])));
        __syncthreads();
    }
    if (t < 32) ts[t] = tensions[t];
    __syncthreads();
    if (t == 0) {
        float mx = ts[0];
        for (int i = 1; i < 32; ++i) mx = fmaxf(mx, ts[i]);
        float s = 0.f, mean = 0.f;
        for (int i = 0; i < 32; ++i) { float e = expf(ts[i] - mx); w[i] = e; s += e; mean += ts[i]; }
        float inv = 1.f / s;
        for (int i = 0; i < 32; ++i) w[i] *= inv;
        out[256] = mean * (1.f / 32.f);
    }
    __syncthreads();
    float c = 0.f;
    for (int i = 0; i < 32; ++i) c += w[i] * outputs[i * 256 + t];
    out[t] = c;
}

extern "C" void kernel_launch(void* const* d_in, const int* in_sizes, int n_in,
                              void* d_out, int out_size, void* d_ws, size_t ws_size,
                              hipStream_t stream) {
    const float* x     = (const float*)d_in[0];
    const float* noise = (const float*)d_in[1];
    const float* ch    = (const float*)d_in[2];
    const float* gW1   = (const float*)d_in[3];
    const float* gb1   = (const float*)d_in[4];
    const float* gW2   = (const float*)d_in[5];
    const float* gb2   = (const float*)d_in[6];
    const float* gW3   = (const float*)d_in[7];
    const float* gb3   = (const float*)d_in[8];
    const float* dW1   = (const float*)d_in[9];
    const float* db1   = (const float*)d_in[10];
    const float* dW2   = (const float*)d_in[11];
    const float* db2   = (const float*)d_in[12];
    const float* dW3   = (const float*)d_in[13];
    const float* db3   = (const float*)d_in[14];
    const float* eaW1  = (const float*)d_in[15];
    const float* eab1  = (const float*)d_in[16];
    const float* eaW2  = (const float*)d_in[17];
    const float* eab2  = (const float*)d_in[18];
    const float* egW1  = (const float*)d_in[19];
    const float* egb1  = (const float*)d_in[20];
    const float* egW2  = (const float*)d_in[21];
    const float* egb2  = (const float*)d_in[22];
    const float* Wih   = (const float*)d_in[23];
    const float* bih   = (const float*)d_in[24];
    const float* Whh   = (const float*)d_in[25];
    const float* bhh   = (const float*)d_in[26];
    const int*   step  = (const int*)d_in[27];

    float* out = (float*)d_out;
    float* ws  = (float*)d_ws;
    float* h1buf    = ws;                 // 256
    float* h2       = h1buf + 256;        // 512
    float* gs       = h2 + 512;           // 262144
    float* fmean    = gs + 262144;        // 2048
    float* outputs  = fmean + 2048;       // 8192
    float* tensions = outputs + 8192;     // 32
    float* d1rp     = tensions + 32;      // 1024
    float* d1fp     = d1rp + 1024;        // 1024
    float* l2buf    = d1fp + 1024;        // 512

    k_gen_h1<<<64, 256, 0, stream>>>(x, noise, gW1, gb1, h1buf);
    k_gen_h2<<<128, 256, 0, stream>>>(h1buf, gW2, gb2, h2);
    k_gen_big<<<FLAT / 16, 256, 0, stream>>>(gW3, gb3, h2, gs);
    k_fmean<<<32, 256, 0, stream>>>(gs, fmean);
    k_mega<<<1056, 1024, 0, stream>>>(dW1, db1, gs, ch, fmean, step, x,
                                      eaW1, eab1, eaW2, eab2,
                                      egW1, egb1, egW2, egb2,
                                      Wih, bih, Whh, bhh,
                                      d1rp, d1fp, outputs, tensions, out);
    k_epi1<<<8, 256, 0, stream>>>(dW2, db2, db1, d1rp, d1fp, l2buf);
    k_epi2<<<1, 256, 0, stream>>>(dW3, db3, l2buf, outputs, tensions, out);
}

// Round 14
// 252.683 us; speedup vs baseline: 2.5465x; 1.0107x over previous
//
#include <hip/hip_runtime.h>
#include <math.h>

#define N_CELLS 1024
#define HID     256
#define IN_DIM  256
#define NOISE_DIM 32
#define OUT_DIM 256
#define N_LOOP  32
#define FLAT    (N_CELLS*HID)   // 262144

typedef float f4 __attribute__((ext_vector_type(4)));

__device__ __forceinline__ float wave_reduce64(float v) {
    #pragma unroll
    for (int m = 32; m; m >>= 1) v += __shfl_xor(v, m);
    return v;
}
__device__ __forceinline__ float dot4(float4 a, float4 b) {
    return a.x*b.x + a.y*b.y + a.z*b.z + a.w*b.w;
}
__device__ __forceinline__ float dot4v(f4 a, float4 b) {
    return a.x*b.x + a.y*b.y + a.z*b.z + a.w*b.w;
}

// ============ h1 = relu(W1.gi + b1), wave-per-row (256 rows x 288) ============
__global__ void k_gen_h1(const float* __restrict__ x, const float* __restrict__ noise,
                         const float* __restrict__ W1, const float* __restrict__ b1,
                         float* __restrict__ h1) {
    __shared__ __align__(16) float gi[288];
    int t = threadIdx.x, l = t & 63, w = t >> 6;
    gi[t] = x[t];
    if (t < 32) gi[256 + t] = noise[t];
    __syncthreads();
    int j = blockIdx.x * 4 + w;
    const float4* wr = (const float4*)(W1 + j * 288);
    const float4* g4 = (const float4*)gi;
    float4 a = wr[l], v = g4[l];
    float acc = dot4(a, v);
    if (l < 8) {
        float4 a2 = wr[64 + l], v2 = g4[64 + l];
        acc += dot4(a2, v2);
    }
    acc = wave_reduce64(acc);
    if (l == 0) h1[j] = fmaxf(acc + b1[j], 0.f);
}

// ============ h2 = relu(W2.h1 + b2), wave-per-row (512 rows x 256) ============
__global__ void k_gen_h2(const float* __restrict__ h1, const float* __restrict__ W2,
                         const float* __restrict__ b2, float* __restrict__ h2) {
    int t = threadIdx.x, l = t & 63, w = t >> 6;
    int j = blockIdx.x * 4 + w;
    float4 a = ((const float4*)(W2 + j * 256))[l];
    float4 v = ((const float4*)h1)[l];
    float acc = dot4(a, v);
    acc = wave_reduce64(acc);
    if (l == 0) h2[j] = fmaxf(acc + b2[j], 0.f);
}

// ============ gen_states = W3.h2 + b3 — 4 rows/wave, NONTEMPORAL W3 stream ============
__global__ void k_gen_big(const float* __restrict__ W3, const float* __restrict__ b3,
                          const float* __restrict__ h2, float* __restrict__ gs) {
    int t = threadIdx.x, l = t & 63, w = t >> 6;
    int r0 = blockIdx.x * 16 + w * 4;            // 16 rows per 256-thr block
    const float4* h24 = (const float4*)h2;
    float4 ha = h24[l], hb = h24[64 + l];
    const f4* w0 = (const f4*)(W3 + (size_t)(r0 + 0) * 512);
    const f4* w1 = (const f4*)(W3 + (size_t)(r0 + 1) * 512);
    const f4* w2 = (const f4*)(W3 + (size_t)(r0 + 2) * 512);
    const f4* w3 = (const f4*)(W3 + (size_t)(r0 + 3) * 512);
    f4 A0 = __builtin_nontemporal_load(w0 + l);
    f4 B0 = __builtin_nontemporal_load(w0 + 64 + l);
    f4 A1 = __builtin_nontemporal_load(w1 + l);
    f4 B1 = __builtin_nontemporal_load(w1 + 64 + l);
    f4 A2 = __builtin_nontemporal_load(w2 + l);
    f4 B2 = __builtin_nontemporal_load(w2 + 64 + l);
    f4 A3 = __builtin_nontemporal_load(w3 + l);
    f4 B3 = __builtin_nontemporal_load(w3 + 64 + l);
    float s0 = dot4v(A0, ha) + dot4v(B0, hb);
    float s1 = dot4v(A1, ha) + dot4v(B1, hb);
    float s2 = dot4v(A2, ha) + dot4v(B2, hb);
    float s3 = dot4v(A3, ha) + dot4v(B3, hb);
    s0 = wave_reduce64(s0);
    s1 = wave_reduce64(s1);
    s2 = wave_reduce64(s2);
    s3 = wave_reduce64(s3);
    if (l == 0) {
        float4 bv = *(const float4*)(b3 + r0);
        float4 o; o.x = s0 + bv.x; o.y = s1 + bv.y; o.z = s2 + bv.z; o.w = s3 + bv.w;
        *(float4*)(gs + r0) = o;
    }
}

// ============ per-faction column means — coalesced f4 reads (verified r11) ============
__global__ void k_fmean(const float* __restrict__ gs, float* __restrict__ fmean) {
    __shared__ __align__(16) f4 part[4][64];
    int f = blockIdx.x, t = threadIdx.x;
    int rg = t >> 6, c4 = t & 63;
    const f4* base = (const f4*)(gs + (size_t)(f * 128 + rg * 32) * 256) + c4;
    f4 acc = {0.f, 0.f, 0.f, 0.f};
    for (int r = 0; r < 32; ++r) acc += base[r * 64];
    part[rg][c4] = acc;
    __syncthreads();
    if (t < 64) {
        f4 v = (part[0][t] + part[1][t]) + (part[2][t] + part[3][t]);
        v *= (1.f / 128.f);
        *(f4*)(fmean + f * 256 + t * 4) = v;
    }
}

// ============ MEGA (1024 thr): blocks 0..31 = per-sample eval+GRU chain,
//   blocks 32..2079 = disc1 quarter-K pieces (row = idx>>2, q = idx&3), NT dW1 ============
__global__ void k_mega(const float* __restrict__ dW1, const float* __restrict__ db1,
                       const float* __restrict__ gs, const float* __restrict__ ch,
                       const float* __restrict__ fmean, const int* __restrict__ step,
                       const float* __restrict__ x,
                       const float* __restrict__ eaW1, const float* __restrict__ eab1,
                       const float* __restrict__ eaW2, const float* __restrict__ eab2,
                       const float* __restrict__ egW1, const float* __restrict__ egb1,
                       const float* __restrict__ egW2, const float* __restrict__ egb2,
                       const float* __restrict__ Wih, const float* __restrict__ bih,
                       const float* __restrict__ Whh, const float* __restrict__ bhh,
                       float* __restrict__ d1rp, float* __restrict__ d1fp,
                       float* __restrict__ outputs, float* __restrict__ tensions,
                       float* __restrict__ out) {
    __shared__ float sR[16];
    __shared__ float sF[16];
    __shared__ __align__(16) float fmL[2048];    // 8 KB: fmean staged
    __shared__ __align__(16) float gmL[256];     // 1 KB: global mean
    __shared__ __align__(16) float xh[512];      // [x | H]
    __shared__ __align__(16) float hag[256];
    __shared__ __align__(16) float outs[256];
    __shared__ float red[256];
    __shared__ float rzA[512];
    __shared__ float inb[256];
    __shared__ float hnb[256];
    __shared__ float tsh;
    int b = blockIdx.x, t = threadIdx.x, l = t & 63, w = t >> 6;
    bool deb = (*step > 5);

    if (b >= 32) {
        // ---- stage fmean + gm into LDS ----
        for (int i = t; i < 2048; i += 1024) fmL[i] = fmean[i];
        __syncthreads();
        if (t < 256) {
            float g = 0.f;
            #pragma unroll
            for (int f = 0; f < 8; ++f) g += fmL[f * 256 + t];
            gmL[t] = g * 0.125f;
        }
        __syncthreads();
        // ---- disc1 quarter-K piece: dot dW1[row][q] vs real(ncn inline) and fake(gs) ----
        int idx = b - 32;
        int row = idx >> 2, qq = idx & 3;
        const f4* w4 = (const f4*)(dW1 + (size_t)row * FLAT);
        const float4* g4 = (const float4*)gs;
        const float4* c4 = (const float4*)ch;
        int kbeg = qq * 16384, kend = kbeg + 16384;
        float aR = 0.f, aF = 0.f;
        for (int i = kbeg + t; i < kend; i += 1024) {
            int c = i >> 6, d4 = i & 63;
            f4 ww = __builtin_nontemporal_load(w4 + i);
            float4 gv = g4[i], cv = c4[i];
            float4 fmv = *(const float4*)(fmL + ((c >> 7) << 8) + d4 * 4);
            float4 v;
            v.x = 0.85f * gv.x + 0.15f * fmv.x;
            v.y = 0.85f * gv.y + 0.15f * fmv.y;
            v.z = 0.85f * gv.z + 0.15f * fmv.z;
            v.w = 0.85f * gv.w + 0.15f * fmv.w;
            if (deb && ((c & 127) < 32)) {
                float4 gm = *(const float4*)(gmL + d4 * 4);
                v.x = 0.85f * v.x + 0.15f * gm.x;
                v.y = 0.85f * v.y + 0.15f * gm.y;
                v.z = 0.85f * v.z + 0.15f * gm.z;
                v.w = 0.85f * v.w + 0.15f * gm.w;
            }
            float4 nc;
            nc.x = 0.7f * v.x + 0.3f * cv.x;
            nc.y = 0.7f * v.y + 0.3f * cv.y;
            nc.z = 0.7f * v.z + 0.3f * cv.z;
            nc.w = 0.7f * v.w + 0.3f * cv.w;
            aR += dot4v(ww, nc);
            aF += dot4v(ww, gv);
        }
        aR = wave_reduce64(aR);
        aF = wave_reduce64(aF);
        if (l == 0) { sR[w] = aR; sF[w] = aF; }
        __syncthreads();
        if (t < 16) {
            float r = sR[t], f = sF[t];
            #pragma unroll
            for (int m = 8; m; m >>= 1) { r += __shfl_xor(r, m); f += __shfl_xor(f, m); }
            if (t == 0) { d1rp[qq * 512 + row] = r; d1fp[qq * 512 + row] = f; }
        }
        return;
    }

    // ---------- per-sample chain, sample i = b (cells 0..31 are faction 0, debate-set) ----------
    int i = b;
    if (t < 256) {
        xh[t] = x[t];
        float g = gs[i * 256 + t];
        float gmv = 0.f;
        #pragma unroll
        for (int f = 0; f < 8; ++f) gmv += fmean[f * 256 + t];
        gmv *= 0.125f;
        float v = 0.85f * g + 0.15f * fmean[t];     // faction 0
        if (deb) v = 0.85f * v + 0.15f * gmv;
        xh[256 + t] = v;
    }
    __syncthreads();

    // ev layer 1: 16 waves x 16 neurons, wave-per-row 512-dot
    for (int k = 0; k < 16; ++k) {
        int j = w * 16 + k;
        const float* W = (j < 128) ? (eaW1 + (size_t)j * 512) : (egW1 + (size_t)(j - 128) * 512);
        const float4* w4 = (const float4*)W;
        const float4* v4 = (const float4*)xh;
        float acc = dot4(w4[l], v4[l]) + dot4(w4[64 + l], v4[64 + l]);
        acc = wave_reduce64(acc);
        if (l == 0) {
            float bias = (j < 128) ? eab1[j] : egb1[j - 128];
            hag[j] = fmaxf(acc + bias, 0.f);
        }
    }
    __syncthreads();

    // ev layer 2: 16 waves x 16 neurons; lanes 0-31 ea(+), 32-63 eg(-)
    for (int k = 0; k < 16; ++k) {
        int tr = w * 16 + k;
        int sl = l & 31;
        bool lo = (l < 32);
        const float4* wv4 = lo ? (const float4*)(eaW2 + (size_t)tr * 128)
                               : (const float4*)(egW2 + (size_t)tr * 128);
        const float4* h4 = (const float4*)(hag + (lo ? 0 : 128));
        float d_ = dot4(wv4[sl], h4[sl]);
        float acc = lo ? d_ : -d_;
        acc = wave_reduce64(acc);
        if (l == 0) {
            float o = acc + eab2[tr] - egb2[tr];
            outs[tr] = o;
            outputs[i * 256 + tr] = o;
        }
    }
    __syncthreads();

    // tension
    if (t < 256) red[t] = outs[t] * outs[t];
    __syncthreads();
    for (int m = 128; m; m >>= 1) { if (t < m && t + m < 256) red[t] += red[t + m]; __syncthreads(); }
    if (t == 0) { float tn = red[0] * (1.f / 256.f); tensions[i] = tn; tsh = tn; }
    __syncthreads();
    float tn = tsh;

    // GRU matvecs: 16 waves x 48 rows (768 rows)
    {
        float4 ov = ((const float4*)outs)[l];
        float4 Hv = ((const float4*)(xh + 256))[l];
        for (int k = 0; k < 48; ++k) {
            int u = w * 48 + k;
            const float* wr = Wih + (size_t)u * 257;
            float g0 = wr[4*l]*ov.x + wr[4*l+1]*ov.y + wr[4*l+2]*ov.z + wr[4*l+3]*ov.w;
            if (l == 0) g0 += wr[256] * tn;
            float4 wh = ((const float4*)(Whh + (size_t)u * 256))[l];
            float h0 = dot4(wh, Hv);
            if (u < 512) {
                float s = wave_reduce64(g0 + h0);
                if (l == 0) rzA[u] = s + bih[u] + bhh[u];
            } else {
                float sg = wave_reduce64(g0);
                float sh = wave_reduce64(h0);
                if (l == 0) { inb[u - 512] = sg + bih[u]; hnb[u - 512] = sh + bhh[u]; }
            }
        }
    }
    __syncthreads();

    // GRU finish
    if (t < 256) {
        float r = 1.f / (1.f + expf(-rzA[t]));
        float z = 1.f / (1.f + expf(-rzA[256 + t]));
        float nc = tanhf(inb[t] + r * hnb[t]);
        float Hd = xh[256 + t];
        out[259 + i * 256 + t] = (1.f - z) * nc + z * Hd;
    }
}

// ============ epi1: sum quarter-K partials (+bias), disc layer-2 GEMV over 8 blocks ============
__global__ void k_epi1(const float* __restrict__ W2, const float* __restrict__ b2,
                       const float* __restrict__ db1,
                       const float* __restrict__ d1rp, const float* __restrict__ d1fp,
                       float* __restrict__ l2buf) {
    __shared__ __align__(16) float lv[512];
    int b = blockIdx.x, t = threadIdx.x, l = t & 63, w = t >> 6;
    int br = b >> 2, q = b & 3;
    const float* dp = br ? d1fp : d1rp;
    for (int j = t; j < 512; j += 256) {
        float v = ((dp[j] + dp[512 + j]) + (dp[1024 + j] + dp[1536 + j])) + db1[j];
        lv[j] = v > 0.f ? v : 0.2f * v;
    }
    __syncthreads();
    const float4* l4 = (const float4*)lv;
    float4 va = l4[l], vb = l4[64 + l];
    for (int k = 0; k < 16; ++k) {
        int tr = q * 64 + w * 16 + k;
        const float4* wr = (const float4*)(W2 + (size_t)tr * 512);
        float acc = dot4(wr[l], va) + dot4(wr[64 + l], vb);
        acc = wave_reduce64(acc);
        if (l == 0) {
            float z = acc + b2[tr];
            l2buf[br * 256 + tr] = z > 0.f ? z : 0.2f * z;
        }
    }
}

// ============ epi2: final disc dots + sigmoid, mean tension, softmax combine ============
__global__ void k_epi2(const float* __restrict__ W3, const float* __restrict__ b3,
                       const float* __restrict__ l2buf,
                       const float* __restrict__ outputs, const float* __restrict__ tensions,
                       float* __restrict__ out) {
    __shared__ float red[256];
    __shared__ float w[32];
    __shared__ float ts[32];
    int t = threadIdx.x;
    for (int p = 0; p < 2; ++p) {
        red[t] = l2buf[p * 256 + t] * W3[t];
        __syncthreads();
        for (int m = 128; m; m >>= 1) { if (t < m) red[t] += red[t + m]; __syncthreads(); }
        if (t == 0) out[257 + p] = 1.f / (1.f + expf(-(red[0] + b3[0])));
        __syncthreads();
    }
    if (t < 32) ts[t] = tensions[t];
    __syncthreads();
    if (t == 0) {
        float mx = ts[0];
        for (int i = 1; i < 32; ++i) mx = fmaxf(mx, ts[i]);
        float s = 0.f, mean = 0.f;
        for (int i = 0; i < 32; ++i) { float e = expf(ts[i] - mx); w[i] = e; s += e; mean += ts[i]; }
        float inv = 1.f / s;
        for (int i = 0; i < 32; ++i) w[i] *= inv;
        out[256] = mean * (1.f / 32.f);
    }
    __syncthreads();
    float c = 0.f;
    for (int i = 0; i < 32; ++i) c += w[i] * outputs[i * 256 + t];
    out[t] = c;
}

extern "C" void kernel_launch(void* const* d_in, const int* in_sizes, int n_in,
                              void* d_out, int out_size, void* d_ws, size_t ws_size,
                              hipStream_t stream) {
    const float* x     = (const float*)d_in[0];
    const float* noise = (const float*)d_in[1];
    const float* ch    = (const float*)d_in[2];
    const float* gW1   = (const float*)d_in[3];
    const float* gb1   = (const float*)d_in[4];
    const float* gW2   = (const float*)d_in[5];
    const float* gb2   = (const float*)d_in[6];
    const float* gW3   = (const float*)d_in[7];
    const float* gb3   = (const float*)d_in[8];
    const float* dW1   = (const float*)d_in[9];
    const float* db1   = (const float*)d_in[10];
    const float* dW2   = (const float*)d_in[11];
    const float* db2   = (const float*)d_in[12];
    const float* dW3   = (const float*)d_in[13];
    const float* db3   = (const float*)d_in[14];
    const float* eaW1  = (const float*)d_in[15];
    const float* eab1  = (const float*)d_in[16];
    const float* eaW2  = (const float*)d_in[17];
    const float* eab2  = (const float*)d_in[18];
    const float* egW1  = (const float*)d_in[19];
    const float* egb1  = (const float*)d_in[20];
    const float* egW2  = (const float*)d_in[21];
    const float* egb2  = (const float*)d_in[22];
    const float* Wih   = (const float*)d_in[23];
    const float* bih   = (const float*)d_in[24];
    const float* Whh   = (const float*)d_in[25];
    const float* bhh   = (const float*)d_in[26];
    const int*   step  = (const int*)d_in[27];

    float* out = (float*)d_out;
    float* ws  = (float*)d_ws;
    float* h1buf    = ws;                 // 256
    float* h2       = h1buf + 256;        // 512
    float* gs       = h2 + 512;           // 262144
    float* fmean    = gs + 262144;        // 2048
    float* outputs  = fmean + 2048;       // 8192
    float* tensions = outputs + 8192;     // 32
    float* d1rp     = tensions + 32;      // 2048
    float* d1fp     = d1rp + 2048;        // 2048
    float* l2buf    = d1fp + 2048;        // 512

    k_gen_h1<<<64, 256, 0, stream>>>(x, noise, gW1, gb1, h1buf);
    k_gen_h2<<<128, 256, 0, stream>>>(h1buf, gW2, gb2, h2);
    k_gen_big<<<FLAT / 16, 256, 0, stream>>>(gW3, gb3, h2, gs);
    k_fmean<<<8, 256, 0, stream>>>(gs, fmean);
    k_mega<<<2080, 1024, 0, stream>>>(dW1, db1, gs, ch, fmean, step, x,
                                      eaW1, eab1, eaW2, eab2,
                                      egW1, egb1, egW2, egb2,
                                      Wih, bih, Whh, bhh,
                                      d1rp, d1fp, outputs, tensions, out);
    k_epi1<<<8, 256, 0, stream>>>(dW2, db2, db1, d1rp, d1fp, l2buf);
    k_epi2<<<1, 256, 0, stream>>>(dW3, db3, l2buf, outputs, tensions, out);
}